// Round 10
// baseline (348.123 us; speedup 1.0000x reference)
//
#include <hip/hip_runtime.h>
#include <math.h>

#define BS 4
#define NC 64
#define CC 256
#define DD 64
#define KK 32
#define ALPHA 8
#define HS 256
#define HM 256
#define HMOD 256
#define MODIN 225   // K + D + 1 + D + D
#define MODOUT 97   // K + 1 + D

// ---------------- Kernel 1: per-(b,n) means over C -> mod_in ----------------
// grid = BS*NC*4; seg 0:h, 1:prim, 2:hebb, 3:dec+mmag (disjoint mi ranges)
__global__ __launch_bounds__(256) void k_means(
    const float* __restrict__ h, const float* __restrict__ dec,
    const float* __restrict__ prim, const float* __restrict__ hebb,
    const float* __restrict__ mmag, float* __restrict__ ws_modin)
{
    const int bn = blockIdx.x >> 2, seg = blockIdx.x & 3;
    const int tid = threadIdx.x;
    __shared__ float4 buf4[256];
    __shared__ float  buf[256];
    const float inv = 1.0f / (float)CC;
    float* mi = ws_modin + (size_t)bn * MODIN;

    if (seg <= 1) {
        const float* src = (seg == 0) ? (h + (size_t)bn * CC * DD)
                                      : (prim + (size_t)bn * CC * DD);
        const int dst = (seg == 0) ? 32 : 97;
        const float4* p4 = (const float4*)src;
        int q = tid & 15, c0 = tid >> 4;
        float4 sum = make_float4(0.f, 0.f, 0.f, 0.f);
        for (int c = c0; c < CC; c += 16) {
            float4 v = p4[c * 16 + q];
            sum.x += v.x; sum.y += v.y; sum.z += v.z; sum.w += v.w;
        }
        buf4[tid] = sum;
        __syncthreads();
        if (tid < 16) {
            float4 t = buf4[tid];
            for (int r = 1; r < 16; r++) {
                float4 v = buf4[r * 16 + tid];
                t.x += v.x; t.y += v.y; t.z += v.z; t.w += v.w;
            }
            mi[dst + tid * 4 + 0] = t.x * inv;
            mi[dst + tid * 4 + 1] = t.y * inv;
            mi[dst + tid * 4 + 2] = t.z * inv;
            mi[dst + tid * 4 + 3] = t.w * inv;
        }
    } else if (seg == 2) {
        const float4* p4 = (const float4*)(hebb + (size_t)bn * CC * KK);
        int q = tid & 7, c0 = tid >> 3;
        float4 sum = make_float4(0.f, 0.f, 0.f, 0.f);
        for (int c = c0; c < CC; c += 32) {
            float4 v = p4[c * 8 + q];
            sum.x += v.x; sum.y += v.y; sum.z += v.z; sum.w += v.w;
        }
        buf4[tid] = sum;
        __syncthreads();
        if (tid < 8) {
            float4 t = buf4[tid];
            for (int r = 1; r < 32; r++) {
                float4 v = buf4[r * 8 + tid];
                t.x += v.x; t.y += v.y; t.z += v.z; t.w += v.w;
            }
            mi[tid * 4 + 0] = t.x * inv;
            mi[tid * 4 + 1] = t.y * inv;
            mi[tid * 4 + 2] = t.z * inv;
            mi[tid * 4 + 3] = t.w * inv;
        }
    } else {
        buf[tid] = dec[(size_t)bn * CC + tid];
        __syncthreads();
        for (int s2 = 128; s2 > 0; s2 >>= 1) {
            if (tid < s2) buf[tid] += buf[tid + s2];
            __syncthreads();
        }
        if (tid == 0) mi[96] = buf[0] * inv;
        __syncthreads();
        buf[tid] = mmag[(size_t)bn * CC + tid];
        __syncthreads();
        for (int s2 = 128; s2 > 0; s2 >>= 1) {
            if (tid < s2) buf[tid] += buf[tid + s2];
            __syncthreads();
        }
        __syncthreads();
        float m = buf[0] * inv;
        if (tid < DD) mi[161 + tid] = m;
    }
}

// ------------- Kernel 2: mod MLP hidden layer, grid = (n, hq, b) = 1024 -----
// thread = (hl 0..63, kq 0..3): split-K-4 dot of mi[b,n] . modw1[n, hq*64+hl]
__global__ __launch_bounds__(256) void k_modhid(
    const float* __restrict__ ws_modin, const float* __restrict__ modw1,
    const float* __restrict__ modb1, float* __restrict__ ws_hid)
{
    const int n = blockIdx.x >> 4, hq = (blockIdx.x >> 2) & 3, b = blockIdx.x & 3;
    const int tid = threadIdx.x;
    __shared__ float mi_s[MODIN + 3];
    __shared__ float red[64][4];
    if (tid < MODIN) mi_s[tid] = ws_modin[(size_t)(b * NC + n) * MODIN + tid];
    __syncthreads();

    const int hl = tid >> 2, kq = tid & 3;
    const int hh = hq * 64 + hl;
    const float* w = modw1 + ((size_t)n * HMOD + hh) * MODIN;
    const int i0 = kq * 57, i1 = (kq == 3) ? MODIN : (i0 + 57);
    float acc = 0.f;
    #pragma unroll 8
    for (int i = i0; i < i1; i++) acc += mi_s[i] * w[i];
    red[hl][kq] = acc;
    __syncthreads();
    if (tid < 64) {
        const int hh2 = hq * 64 + tid;
        float v = red[tid][0] + red[tid][1] + red[tid][2] + red[tid][3]
                + modb1[n * HMOD + hh2];
        ws_hid[(size_t)(b * NC + n) * HMOD + hh2] = tanhf(v);
    }
}

// ------------- Kernel 3: per-(b,n), 1024 thr; modout + nid inline + cells ---
__global__ __launch_bounds__(1024) void k_cells(
    const float* __restrict__ h, const float* __restrict__ pm,
    const int* __restrict__ conn,
    const float* __restrict__ sw1, const float* __restrict__ sb1,
    const float* __restrict__ sw2, const float* __restrict__ sb2,
    const float* __restrict__ mw1, const float* __restrict__ mb1,
    const float* __restrict__ mw2, const float* __restrict__ mb2,
    const float* __restrict__ nid_g, const float* __restrict__ ws_hid,
    const float* __restrict__ modw2, const float* __restrict__ modb2,
    float* __restrict__ out)
{
    const int b = blockIdx.x >> 6, n = blockIdx.x & 63;
    const int tid = threadIdx.x;

    __shared__ float wsig[KK];
    __shared__ alignas(16) float prm[DD];
    __shared__ int cidx[ALPHA][KK];
    __shared__ alignas(16) float nid_s[ALPHA][DD];
    __shared__ alignas(16) float iv[ALPHA][DD];
    __shared__ alignas(16) float hnew[ALPHA][DD];
    __shared__ alignas(16) float t1[ALPHA][HS];
    __shared__ alignas(16) float hm[ALPHA][HM];
    __shared__ float red[1024];
    __shared__ float base_s_sh[HS], base_m_sh[HM];
    __shared__ float hidv[HMOD];
    __shared__ float sdecay_sh, ssig_sh;

    const size_t pmbase = (size_t)(b * NC + n) * CC * DD;

    // ---- phase 0a: loads (disjoint tid ranges) ----------------------------
    if (tid < 256) {
        hidv[tid] = ws_hid[(size_t)(b * NC + n) * HMOD + tid];
    } else if (tid < 512) {
        int j = tid - 256, a = j >> 5, k = j & 31;
        cidx[a][k] = conn[((size_t)n * CC + (CC - ALPHA + a)) * KK + k];
    } else {
        int j = tid - 512, a = j >> 6, d = j & 63;
        nid_s[a][d] = nid_g[((size_t)n * CC + (CC - ALPHA + a)) * DD + d];
    }
    __syncthreads();

    // ---- phase 0b: mod output layer (o coalesced, split-K-8) --------------
    {
        const int o = tid & 127, kq = tid >> 7;
        float acc = 0.f;
        if (o < MODOUT) {
            const float* w = modw2 + ((size_t)n * HMOD + kq * 32) * MODOUT + o;
            #pragma unroll
            for (int j = 0; j < 32; j++) acc += hidv[kq * 32 + j] * w[(size_t)j * MODOUT];
        }
        red[tid] = acc;
    }
    __syncthreads();
    if (tid < 128) {
        const int o = tid;
        if (o < MODOUT) {
            float v = modb2[n * MODOUT + o];
            #pragma unroll
            for (int kq = 0; kq < 8; kq++) v += red[o + 128 * kq];
            if (o < KK) wsig[o] = 1.0f / (1.0f + expf(-v));
            else if (o == KK) {
                sdecay_sh = v;
                ssig_sh = 1.0f / (1.0f + expf(-v));
            } else prm[o - KK - 1] = v;
        }
    }
    __syncthreads();

    // ---- phase 1 (parallel waves): base_s | base_m | gather ---------------
    if (tid < 256) {
        const int hh = tid;
        const float* w = sw1 + (size_t)hh * 193;
        float acc = sb1[hh] + sdecay_sh * w[192];
        for (int d = 0; d < DD; d++) acc += prm[d] * w[64 + d];
        base_s_sh[hh] = acc;
    } else if (tid < 512) {
        const int hh = tid - 256;
        const float4* w4 = (const float4*)(mw1 + (size_t)hh * 192 + 64);
        const float4* p4 = (const float4*)prm;
        float acc = mb1[hh];
        #pragma unroll
        for (int d4 = 0; d4 < 16; d4++) {
            float4 wv = w4[d4], pv = p4[d4];
            acc += wv.x * pv.x + wv.y * pv.y + wv.z * pv.z + wv.w * pv.w;
        }
        base_m_sh[hh] = acc;
    } else {
        const int j = tid - 512, a = j >> 6, d = j & 63;
        float acc = 0.f;
        #pragma unroll 8
        for (int k = 0; k < KK; k++)
            acc += wsig[k] * pm[pmbase + (size_t)cidx[a][k] * DD + d];
        iv[a][d] = acc;
    }
    __syncthreads();

    // ---- phase 2: state hidden, thread = (hh, cell-pair) -------------------
    {
        const int hh = tid & 255, g = tid >> 8;
        const int a0 = g * 2, a1 = g * 2 + 1;
        const float* w = sw1 + (size_t)hh * 193;
        float acc0 = base_s_sh[hh], acc1 = acc0;
        #pragma unroll
        for (int d4 = 0; d4 < 16; d4++) {
            float w0 = w[d4 * 4], w1 = w[d4 * 4 + 1],
                  w2 = w[d4 * 4 + 2], w3 = w[d4 * 4 + 3];
            float4 v0 = ((const float4*)iv[a0])[d4];
            float4 v1 = ((const float4*)iv[a1])[d4];
            acc0 += v0.x * w0 + v0.y * w1 + v0.z * w2 + v0.w * w3;
            acc1 += v1.x * w0 + v1.y * w1 + v1.z * w2 + v1.w * w3;
            float u0 = w[128 + d4 * 4], u1 = w[128 + d4 * 4 + 1],
                  u2 = w[128 + d4 * 4 + 2], u3 = w[128 + d4 * 4 + 3];
            float4 n0 = ((const float4*)nid_s[a0])[d4];
            float4 n1 = ((const float4*)nid_s[a1])[d4];
            acc0 += n0.x * u0 + n0.y * u1 + n0.z * u2 + n0.w * u3;
            acc1 += n1.x * u0 + n1.y * u1 + n1.z * u2 + n1.w * u3;
        }
        t1[a0][hh] = tanhf(acc0);
        t1[a1][hh] = tanhf(acc1);
    }
    __syncthreads();

    // ---- phase 3: state out + h_new, thread = (d, a, hh-half) --------------
    {
        const int d = tid & 63, a = (tid >> 6) & 7, half = tid >> 9;
        const float4* w4 = (const float4*)(sw2 + (size_t)d * HS + half * 128);
        const float4* t4 = ((const float4*)t1[a]) + half * 32;
        float acc = 0.f;
        #pragma unroll
        for (int j = 0; j < 32; j++) {
            float4 wv = w4[j], tv = t4[j];
            acc += wv.x * tv.x + wv.y * tv.y + wv.z * tv.z + wv.w * tv.w;
        }
        red[tid] = acc;
    }
    __syncthreads();
    if (tid < 512) {
        const int d = tid & 63, a = tid >> 6;
        float u = tanhf(red[tid] + red[tid + 512] + sb2[d]);
        float hv = h[pmbase + (size_t)(CC - ALPHA + a) * DD + d];
        hnew[a][d] = ssig_sh * hv + (1.f - ssig_sh) * u;
    }
    __syncthreads();

    // ---- phase 4: msg hidden ----------------------------------------------
    {
        const int hh = tid & 255, g = tid >> 8;
        const int a0 = g * 2, a1 = g * 2 + 1;
        const float4* w4 = (const float4*)(mw1 + (size_t)hh * 192);
        float acc0 = base_m_sh[hh], acc1 = acc0;
        #pragma unroll
        for (int d4 = 0; d4 < 16; d4++) {
            float4 wv = w4[d4];
            float4 v0 = ((const float4*)hnew[a0])[d4];
            float4 v1 = ((const float4*)hnew[a1])[d4];
            acc0 += wv.x * v0.x + wv.y * v0.y + wv.z * v0.z + wv.w * v0.w;
            acc1 += wv.x * v1.x + wv.y * v1.y + wv.z * v1.z + wv.w * v1.w;
            float4 uv = w4[32 + d4];
            float4 n0 = ((const float4*)nid_s[a0])[d4];
            float4 n1 = ((const float4*)nid_s[a1])[d4];
            acc0 += uv.x * n0.x + uv.y * n0.y + uv.z * n0.z + uv.w * n0.w;
            acc1 += uv.x * n1.x + uv.y * n1.y + uv.z * n1.z + uv.w * n1.w;
        }
        hm[a0][hh] = tanhf(acc0);
        hm[a1][hh] = tanhf(acc1);
    }
    __syncthreads();

    // ---- phase 5: msg out + readout ---------------------------------------
    {
        const int d = tid & 63, a = (tid >> 6) & 7, half = tid >> 9;
        const float4* w4 = (const float4*)(mw2 + (size_t)d * HM + half * 128);
        const float4* m4 = ((const float4*)hm[a]) + half * 32;
        float acc = 0.f;
        #pragma unroll
        for (int j = 0; j < 32; j++) {
            float4 wv = w4[j], mv = m4[j];
            acc += wv.x * mv.x + wv.y * mv.y + wv.z * mv.z + wv.w * mv.w;
        }
        red[tid] = acc;
    }
    __syncthreads();
    float mval = 0.f;
    if (tid < 512) {
        const int d = tid & 63;
        mval = tanhf(red[tid] + red[tid + 512] + mb2[d]);
    }
    __syncthreads();
    if (tid < 512) red[tid] = mval;
    __syncthreads();
    if (tid < DD) {
        float s = 0.f;
        #pragma unroll
        for (int a = 0; a < ALPHA; a++) s += red[a * 64 + tid];
        out[(size_t)(b * NC + n) * DD + tid] = s * 0.125f;
    }
}

extern "C" void kernel_launch(void* const* d_in, const int* in_sizes, int n_in,
                              void* d_out, int out_size, void* d_ws, size_t ws_size,
                              hipStream_t stream) {
    const float* h     = (const float*)d_in[0];
    const float* pm    = (const float*)d_in[1];
    const float* dec   = (const float*)d_in[2];
    const float* prim  = (const float*)d_in[3];
    const float* hebb  = (const float*)d_in[4];
    const float* mmag  = (const float*)d_in[5];
    // d_in[6] cc_signals: provably unused (injection hits cells 0..7 only;
    // readout reads cells 248..255). Confirmed by round-2 pass (absmax 1.2e-4).
    const float* sw1   = (const float*)d_in[7];
    const float* sb1   = (const float*)d_in[8];
    const float* sw2   = (const float*)d_in[9];
    const float* sb2   = (const float*)d_in[10];
    const float* mw1   = (const float*)d_in[11];
    const float* mb1   = (const float*)d_in[12];
    const float* mw2   = (const float*)d_in[13];
    const float* mb2   = (const float*)d_in[14];
    const float* modw1 = (const float*)d_in[15];
    const float* modb1 = (const float*)d_in[16];
    const float* modw2 = (const float*)d_in[17];
    const float* modb2 = (const float*)d_in[18];
    const float* nid   = (const float*)d_in[19];
    const int*   conn  = (const int*)d_in[20];
    float* out = (float*)d_out;

    float* ws       = (float*)d_ws;
    float* ws_modin = ws;                       // 256*225 = 57600 floats
    float* ws_hid   = ws + 57600;               // 256*256 = 65536 floats

    k_means <<<BS * NC * 4, 256, 0, stream>>>(h, dec, prim, hebb, mmag, ws_modin);
    k_modhid<<<NC * 4 * BS, 256, 0, stream>>>(ws_modin, modw1, modb1, ws_hid);
    k_cells <<<BS * NC, 1024, 0, stream>>>(h, pm, conn, sw1, sb1, sw2, sb2,
                                           mw1, mb1, mw2, mb2, nid, ws_hid,
                                           modw2, modb2, out);
}